// Round 8
// baseline (1193.470 us; speedup 1.0000x reference)
//
#include <hip/hip_runtime.h>
#include <hip/hip_bf16.h>

#define HID 160
#define LM 768

__device__ __forceinline__ float leaky(float x) { return x > 0.0f ? x : 0.01f * x; }

// ---------------- CSR build ----------------
__global__ __launch_bounds__(256) void count_deg_kernel(const int* __restrict__ ei, int* __restrict__ deg, int E) {
    int e = blockIdx.x * 256 + threadIdx.x;
    if (e < E) atomicAdd(&deg[ei[E + e]], 1);
}

__global__ __launch_bounds__(1024) void scan_kernel(const int* __restrict__ deg, int* __restrict__ rowstart,
                                                    float* __restrict__ invd, int N) {
    __shared__ int wsum[16];
    __shared__ int carry_s;
    int t = threadIdx.x;
    int lane = t & 63;
    int w = t >> 6;
    if (t == 0) carry_s = 0;
    __syncthreads();
    for (int base = 0; base < N; base += 1024) {
        int i = base + t;
        int v = (i < N) ? deg[i] : 0;
        int x = v;
        #pragma unroll
        for (int off = 1; off < 64; off <<= 1) {
            int y = __shfl_up(x, off);
            x = (lane >= off) ? x + y : x;
        }
        if (lane == 63) wsum[w] = x;
        __syncthreads();
        int woff = 0;
        for (int k = 0; k < w; k++) woff += wsum[k];
        int excl = carry_s + woff + x - v;
        if (i < N) {
            rowstart[i] = excl;
            invd[i] = 1.0f / (float)(v > 0 ? v : 1);
        }
        __syncthreads();
        if (t == 1023) carry_s += woff + x;
        __syncthreads();
    }
}

__global__ __launch_bounds__(256) void fill_csr_kernel(const int* __restrict__ ei, const int* __restrict__ rowstart,
                                                       int* __restrict__ cursor, int* __restrict__ csr, int E) {
    int e = blockIdx.x * 256 + threadIdx.x;
    if (e < E) {
        int d = ei[E + e];
        int p = atomicAdd(&cursor[d], 1);
        csr[rowstart[d] + p] = ei[e];
    }
}

// ---------------- encoder: three 768->32 GEMMs (z picks input) ----------------
// v3: W via wave-uniform SCALAR loads (SGPR, no LDS) -> LDS pipe serves only A.
// 4 waves/block; wave wq owns 8 output cols; 64 lanes x 2 rows = 128-row tile.
// LDS reads: 32 b128/wave/K-tile (was 96). FMA:LDS ratio 5.3 -> 32.
#define ETM 128
__global__ __launch_bounds__(256, 4) void enc768_kernel(
    const float* __restrict__ des, const float* __restrict__ twt, const float* __restrict__ xx,
    const float* __restrict__ Wd, const float* __restrict__ Wt, const float* __restrict__ Wx,
    const float* __restrict__ bd, const float* __restrict__ bt, const float* __restrict__ bx,
    float* __restrict__ H0, int N) {
    __shared__ float As[ETM * 68];
    int t = threadIdx.x;
    int z = blockIdx.z;
    const float* A = z == 0 ? des : (z == 1 ? twt : xx);
    const float* W = z == 0 ? Wd : (z == 1 ? Wt : Wx);
    const float* b = z == 0 ? bd : (z == 1 ? bt : bx);
    int colOff = 64 + 32 * z;
    int b0 = blockIdx.x * ETM;
    int lane = t & 63;
    int wq = __builtin_amdgcn_readfirstlane(t >> 6);  // wave id -> 8-col slice (SGPR)
    float acc0[8] = {};
    float acc1[8] = {};
    for (int kb = 0; kb < LM; kb += 64) {
        __syncthreads();
        // stage A: 128 rows x 64 k = 2048 float4; 8 per thread (coalesced)
        #pragma unroll
        for (int i = 0; i < 8; i++) {
            int f = t + 256 * i;
            int row = f >> 4, kq = f & 15;
            int gr = b0 + row;
            float4 v = make_float4(0.f, 0.f, 0.f, 0.f);
            if (gr < N) v = *(const float4*)(A + (size_t)gr * LM + kb + 4 * kq);
            *(float4*)(&As[row * 68 + 4 * kq]) = v;
        }
        __syncthreads();
        #pragma unroll 4
        for (int k4 = 0; k4 < 16; k4++) {
            float4 a0 = *(const float4*)(&As[lane * 68 + 4 * k4]);
            float4 a1 = *(const float4*)(&As[(lane + 64) * 68 + 4 * k4]);
            float a0v[4] = {a0.x, a0.y, a0.z, a0.w};
            float a1v[4] = {a1.x, a1.y, a1.z, a1.w};
            #pragma unroll
            for (int j = 0; j < 4; j++) {
                const float* Wk = W + (size_t)(kb + 4 * k4 + j) * 32 + 8 * wq;  // wave-uniform -> s_load
                #pragma unroll
                for (int c = 0; c < 8; c++) {
                    float wv = Wk[c];
                    acc0[c] += a0v[j] * wv;
                    acc1[c] += a1v[j] * wv;
                }
            }
        }
    }
    const float* bp = b + 8 * wq;  // wave-uniform
    int gr0 = b0 + lane;
    if (gr0 < N) {
        float* Hr = H0 + (size_t)gr0 * HID + colOff + 8 * wq;
        float4 o;
        o.x = leaky(acc0[0] + bp[0]); o.y = leaky(acc0[1] + bp[1]);
        o.z = leaky(acc0[2] + bp[2]); o.w = leaky(acc0[3] + bp[3]);
        *(float4*)(Hr) = o;
        o.x = leaky(acc0[4] + bp[4]); o.y = leaky(acc0[5] + bp[5]);
        o.z = leaky(acc0[6] + bp[6]); o.w = leaky(acc0[7] + bp[7]);
        *(float4*)(Hr + 4) = o;
    }
    int gr1 = b0 + lane + 64;
    if (gr1 < N) {
        float* Hr = H0 + (size_t)gr1 * HID + colOff + 8 * wq;
        float4 o;
        o.x = leaky(acc1[0] + bp[0]); o.y = leaky(acc1[1] + bp[1]);
        o.z = leaky(acc1[2] + bp[2]); o.w = leaky(acc1[3] + bp[3]);
        *(float4*)(Hr) = o;
        o.x = leaky(acc1[4] + bp[4]); o.y = leaky(acc1[5] + bp[5]);
        o.z = leaky(acc1[6] + bp[6]); o.w = leaky(acc1[7] + bp[7]);
        *(float4*)(Hr + 4) = o;
    }
}

// ---------------- encoder: num_prop (6->32) + num_category (11->32) ----------------
__global__ __launch_bounds__(256) void enc_small_kernel(
    const float* __restrict__ npr, const float* __restrict__ ncat,
    const float* __restrict__ Wnp, const float* __restrict__ bnp,
    const float* __restrict__ Wnc, const float* __restrict__ bnc,
    float* __restrict__ H0, int N) {
    __shared__ float sWnp[192], sbnp[32], sWnc[352], sbnc[32];
    int t = threadIdx.x;
    if (t < 192) sWnp[t] = Wnp[t];
    for (int i = t; i < 352; i += 256) sWnc[i] = Wnc[i];
    if (t < 32) { sbnp[t] = bnp[t]; sbnc[t] = bnc[t]; }
    __syncthreads();
    int i = blockIdx.x * 256 + t;
    if (i >= N) return;
    float a[11];
    #pragma unroll
    for (int j = 0; j < 6; j++) a[j] = npr[(size_t)i * 6 + j];
    float o[32];
    #pragma unroll
    for (int c = 0; c < 32; c++) {
        float s = sbnp[c];
        #pragma unroll
        for (int j = 0; j < 6; j++) s += a[j] * sWnp[j * 32 + c];
        o[c] = leaky(s);
    }
    #pragma unroll
    for (int q = 0; q < 8; q++)
        *(float4*)(H0 + (size_t)i * HID + 4 * q) = make_float4(o[4 * q], o[4 * q + 1], o[4 * q + 2], o[4 * q + 3]);
    #pragma unroll
    for (int j = 0; j < 11; j++) a[j] = ncat[(size_t)i * 11 + j];
    #pragma unroll
    for (int c = 0; c < 32; c++) {
        float s = sbnc[c];
        #pragma unroll
        for (int j = 0; j < 11; j++) s += a[j] * sWnc[j * 32 + c];
        o[c] = leaky(s);
    }
    #pragma unroll
    for (int q = 0; q < 8; q++)
        *(float4*)(H0 + (size_t)i * HID + 32 + 4 * q) = make_float4(o[4 * q], o[4 * q + 1], o[4 * q + 2], o[4 * q + 3]);
}

// ---------------- 160x160 GEMM (optionally dual-source, optional leaky) ----------------
// v2: scalar-W (same trick as enc768 v3). 4 waves x 40 cols; 128-row tile.
// LDS only for A (18 KB). In-place C==A1 or C==A2 safe (row-partitioned).
template <bool DUAL, bool ACT>
__global__ __launch_bounds__(256) void gemm160_kernel(
    const float* __restrict__ A1, const float* __restrict__ W1,
    const float* __restrict__ A2, const float* __restrict__ W2,
    const float* __restrict__ bias, float* __restrict__ C, int N) {
    __shared__ float As[128 * 36];
    int t = threadIdx.x;
    int b0 = blockIdx.x * 128;
    int lane = t & 63;
    int wq = __builtin_amdgcn_readfirstlane(t >> 6);  // wave -> 40-col slice
    float acc0[40] = {};
    float acc1[40] = {};
    const int NP = DUAL ? 2 : 1;
    for (int p = 0; p < NP; p++) {
        const float* A = (p == 0) ? A1 : A2;
        const float* W = (p == 0) ? W1 : W2;
        for (int kb = 0; kb < HID; kb += 32) {
            __syncthreads();
            // stage A: 128 rows x 32 k = 1024 float4; 4 per thread
            #pragma unroll
            for (int i = 0; i < 4; i++) {
                int f = t + 256 * i;
                int row = f >> 3, kq = f & 7;
                int gr = b0 + row;
                float4 v = make_float4(0.f, 0.f, 0.f, 0.f);
                if (gr < N) v = *(const float4*)(A + (size_t)gr * HID + kb + 4 * kq);
                *(float4*)(&As[row * 36 + 4 * kq]) = v;
            }
            __syncthreads();
            for (int k4 = 0; k4 < 8; k4++) {
                float4 a0 = *(const float4*)(&As[lane * 36 + 4 * k4]);
                float4 a1 = *(const float4*)(&As[(lane + 64) * 36 + 4 * k4]);
                float a0v[4] = {a0.x, a0.y, a0.z, a0.w};
                float a1v[4] = {a1.x, a1.y, a1.z, a1.w};
                #pragma unroll
                for (int j = 0; j < 4; j++) {
                    const float* Wk = W + (size_t)(kb + 4 * k4 + j) * HID + 40 * wq;  // uniform -> s_load
                    #pragma unroll
                    for (int c = 0; c < 40; c++) {
                        float wv = Wk[c];
                        acc0[c] += a0v[j] * wv;
                        acc1[c] += a1v[j] * wv;
                    }
                }
            }
        }
    }
    const float* bp = bias + 40 * wq;  // uniform
    int gr0 = b0 + lane;
    if (gr0 < N) {
        float* Cr = C + (size_t)gr0 * HID + 40 * wq;
        #pragma unroll
        for (int q = 0; q < 10; q++) {
            float4 o;
            o.x = acc0[4 * q + 0] + bp[4 * q + 0];
            o.y = acc0[4 * q + 1] + bp[4 * q + 1];
            o.z = acc0[4 * q + 2] + bp[4 * q + 2];
            o.w = acc0[4 * q + 3] + bp[4 * q + 3];
            if (ACT) { o.x = leaky(o.x); o.y = leaky(o.y); o.z = leaky(o.z); o.w = leaky(o.w); }
            *(float4*)(Cr + 4 * q) = o;
        }
    }
    int gr1 = b0 + lane + 64;
    if (gr1 < N) {
        float* Cr = C + (size_t)gr1 * HID + 40 * wq;
        #pragma unroll
        for (int q = 0; q < 10; q++) {
            float4 o;
            o.x = acc1[4 * q + 0] + bp[4 * q + 0];
            o.y = acc1[4 * q + 1] + bp[4 * q + 1];
            o.z = acc1[4 * q + 2] + bp[4 * q + 2];
            o.w = acc1[4 * q + 3] + bp[4 * q + 3];
            if (ACT) { o.x = leaky(o.x); o.y = leaky(o.y); o.z = leaky(o.z); o.w = leaky(o.w); }
            *(float4*)(Cr + 4 * q) = o;
        }
    }
}

// ---------------- mean aggregation over CSR: one wave per node ----------------
__global__ __launch_bounds__(256) void agg_kernel(const float* __restrict__ H,
                                                  const int* __restrict__ rowstart, const int* __restrict__ deg,
                                                  const int* __restrict__ csr, const float* __restrict__ invd,
                                                  float* __restrict__ M, int N) {
    int wid = (blockIdx.x * 256 + threadIdx.x) >> 6;
    int lane = threadIdx.x & 63;
    if (wid >= N) return;
    int rs = rowstart[wid];
    int d = deg[wid];
    float inv = invd[wid];
    if (lane < 40) {
        float4 acc = make_float4(0.f, 0.f, 0.f, 0.f);
        const float4* Hv = (const float4*)H;
        for (int j = 0; j < d; j++) {
            int s = csr[rs + j];
            float4 v = Hv[(size_t)s * 40 + lane];
            acc.x += v.x; acc.y += v.y; acc.z += v.z; acc.w += v.w;
        }
        float4 o = make_float4(acc.x * inv, acc.y * inv, acc.z * inv, acc.w * inv);
        ((float4*)M)[(size_t)wid * 40 + lane] = o;
    }
}

// ---------------- output head: out = em @ W_o2 + b_o2 ----------------
__global__ __launch_bounds__(256) void out_head_kernel(const float* __restrict__ em,
                                                       const float* __restrict__ Wo2, const float* __restrict__ bo2,
                                                       float* __restrict__ out, int N) {
    __shared__ float sW[320];
    __shared__ float sb[2];
    int t = threadIdx.x;
    for (int i = t; i < 320; i += 256) sW[i] = Wo2[i];
    if (t < 2) sb[t] = bo2[t];
    __syncthreads();
    int i = blockIdx.x * 256 + t;
    if (i >= N) return;
    const float4* er = (const float4*)em + (size_t)i * 40;
    float ax = sb[0], ay = sb[1];
    #pragma unroll 4
    for (int q = 0; q < 40; q++) {
        float4 v = er[q];
        int k = 8 * q;
        ax += v.x * sW[k + 0] + v.y * sW[k + 2] + v.z * sW[k + 4] + v.w * sW[k + 6];
        ay += v.x * sW[k + 1] + v.y * sW[k + 3] + v.z * sW[k + 5] + v.w * sW[k + 7];
    }
    out[2 * i + 0] = ax;
    out[2 * i + 1] = ay;
}

extern "C" void kernel_launch(void* const* d_in, const int* in_sizes, int n_in,
                              void* d_out, int out_size, void* d_ws, size_t ws_size,
                              hipStream_t stream) {
    const float* x        = (const float*)d_in[0];
    const int*   ei       = (const int*)d_in[1];
    const float* num_prop = (const float*)d_in[2];
    const float* num_cat  = (const float*)d_in[3];
    const float* des      = (const float*)d_in[4];
    const float* twt      = (const float*)d_in[5];
    const float* W_des = (const float*)d_in[6],  *b_des = (const float*)d_in[7];
    const float* W_tw  = (const float*)d_in[8],  *b_tw  = (const float*)d_in[9];
    const float* W_txt = (const float*)d_in[10], *b_txt = (const float*)d_in[11];
    const float* W_np  = (const float*)d_in[12], *b_np  = (const float*)d_in[13];
    const float* W_nc  = (const float*)d_in[14], *b_nc  = (const float*)d_in[15];
    const float* W_in  = (const float*)d_in[16], *b_in  = (const float*)d_in[17];
    const float* W_l   = (const float*)d_in[18], *b_l   = (const float*)d_in[19];
    const float* W_r   = (const float*)d_in[20];
    const float* W_o1  = (const float*)d_in[21], *b_o1  = (const float*)d_in[22];
    const float* W_o2  = (const float*)d_in[23], *b_o2  = (const float*)d_in[24];

    const int N = in_sizes[0] / LM;
    const int E = in_sizes[1] / 2;

    float* bufA = (float*)d_ws;
    float* bufB = bufA + (size_t)N * HID;
    int* deg      = (int*)(bufB + (size_t)N * HID);
    int* cursor   = deg + N;
    int* rowstart = cursor + N;
    float* invd   = (float*)(rowstart + N);
    int* csr      = (int*)(invd + N);

    float* out_ptr = (float*)d_out;            // [N,2]
    float* em_ptr  = out_ptr + (size_t)N * 2;  // [N,160]

    // CSR build (reused by both convs)
    hipMemsetAsync(deg, 0, sizeof(int) * (size_t)(2 * N), stream);  // deg + cursor
    count_deg_kernel<<<(E + 255) / 256, 256, 0, stream>>>(ei, deg, E);
    scan_kernel<<<1, 1024, 0, stream>>>(deg, rowstart, invd, N);
    fill_csr_kernel<<<(E + 255) / 256, 256, 0, stream>>>(ei, rowstart, cursor, csr, E);

    // feature encoders -> h0 in bufA
    dim3 egrid((N + ETM - 1) / ETM, 1, 3);
    enc768_kernel<<<egrid, 256, 0, stream>>>(des, twt, x, W_des, W_tw, W_txt, b_des, b_tw, b_txt, bufA, N);
    enc_small_kernel<<<(N + 255) / 256, 256, 0, stream>>>(num_prop, num_cat, W_np, b_np, W_nc, b_nc, bufA, N);

    int g128 = (N + 127) / 128;
    // h1 = leaky(h0 @ W_in + b_in)  : bufA -> bufB
    gemm160_kernel<false, true><<<g128, 256, 0, stream>>>(bufA, W_in, nullptr, nullptr, b_in, bufB, N);
    // mean1 = agg(h1)               : bufB -> bufA
    agg_kernel<<<(N + 3) / 4, 256, 0, stream>>>(bufB, rowstart, deg, csr, invd, bufA, N);
    // h2 = mean1 @ W_l + h1 @ W_r + b_l : (bufA,bufB) -> bufA (in-place safe)
    gemm160_kernel<true, false><<<g128, 256, 0, stream>>>(bufA, W_l, bufB, W_r, b_l, bufA, N);
    // mean2 = agg(h2)               : bufA -> bufB
    agg_kernel<<<(N + 3) / 4, 256, 0, stream>>>(bufA, rowstart, deg, csr, invd, bufB, N);
    // h3 = mean2 @ W_l + h2 @ W_r + b_l : (bufB,bufA) -> bufB
    gemm160_kernel<true, false><<<g128, 256, 0, stream>>>(bufB, W_l, bufA, W_r, b_l, bufB, N);
    // em = leaky(h3 @ W_o1 + b_o1)  : bufB -> em (d_out)
    gemm160_kernel<false, true><<<g128, 256, 0, stream>>>(bufB, W_o1, nullptr, nullptr, b_o1, em_ptr, N);
    // out = em @ W_o2 + b_o2
    out_head_kernel<<<(N + 255) / 256, 256, 0, stream>>>(em_ptr, W_o2, b_o2, out_ptr, N);
}